// Round 6
// baseline (313.144 us; speedup 1.0000x reference)
//
#include <hip/hip_runtime.h>

#define NB 16
#define NC 512
#define NSP 1024
#define OQKV 1536
#define EPSV 1e-5f

typedef unsigned short u16;
typedef unsigned int u32;
typedef __attribute__((ext_vector_type(8))) short short8;
typedef __attribute__((ext_vector_type(4))) float f32x4;

__device__ __forceinline__ float us2f(u16 u) {
  return __uint_as_float(((u32)u) << 16);
}
__device__ __forceinline__ u16 f2us(float f) {  // RNE f32->bf16
  u32 x = __float_as_uint(f);
  return (u16)((x + 0x7fffu + ((x >> 16) & 1u)) >> 16);
}
#if __has_builtin(__builtin_amdgcn_cvt_pk_bf16_f32)
typedef __attribute__((ext_vector_type(2))) __bf16 bf16x2_t;
__device__ __forceinline__ u32 pack2(float a, float b) {
  bf16x2_t r = __builtin_amdgcn_cvt_pk_bf16_f32(a, b);
  return *reinterpret_cast<u32*>(&r);
}
#else
__device__ __forceinline__ u32 pack2(float a, float b) {
  return (u32)f2us(a) | ((u32)f2us(b) << 16);
}
#endif
__device__ __forceinline__ float ld1(const void* p, size_t i, bool f32) {
  return f32 ? ((const float*)p)[i] : us2f(((const u16*)p)[i]);
}
// wave-uniform input-dtype detection (fp32 low-halves are random mantissa)
__device__ __forceinline__ bool detect_f32(const void* x0) {
  const u32* xw = (const u32*)x0;
  u32 w = xw[threadIdx.x & 63];
  u32 e = ((w & 0xffffu) >> 7) & 0xffu;
  bool sane = (e >= 0x60u && e <= 0x9fu);
  return __popcll(__ballot(sane)) < 32;
}

// ---- GroupNorm stats: one block per (b,g) ----
__global__ __launch_bounds__(256) void gn_stats_kernel(
    const void* __restrict__ x, float2* __restrict__ stats) {
  bool f32 = detect_f32(x);
  int idx = blockIdx.x;
  size_t base = (size_t)idx * 65536;
  float s1 = 0.f, s2 = 0.f;
  for (int i = threadIdx.x; i < 8192; i += 256) {
    float f[8];
    if (f32) {
      float4 a = *((const float4*)x + (base >> 2) + i * 2);
      float4 b = *((const float4*)x + (base >> 2) + i * 2 + 1);
      f[0]=a.x; f[1]=a.y; f[2]=a.z; f[3]=a.w; f[4]=b.x; f[5]=b.y; f[6]=b.z; f[7]=b.w;
    } else {
      uint4 p = *((const uint4*)x + (base >> 3) + i);
      f[0]=us2f((u16)(p.x&0xffffu)); f[1]=us2f((u16)(p.x>>16));
      f[2]=us2f((u16)(p.y&0xffffu)); f[3]=us2f((u16)(p.y>>16));
      f[4]=us2f((u16)(p.z&0xffffu)); f[5]=us2f((u16)(p.z>>16));
      f[6]=us2f((u16)(p.w&0xffffu)); f[7]=us2f((u16)(p.w>>16));
    }
#pragma unroll
    for (int m = 0; m < 8; m++) { s1 += f[m]; s2 += f[m] * f[m]; }
  }
  __shared__ float r1[256], r2[256];
  r1[threadIdx.x] = s1; r2[threadIdx.x] = s2;
  __syncthreads();
  for (int s = 128; s > 0; s >>= 1) {
    if ((int)threadIdx.x < s) {
      r1[threadIdx.x] += r1[threadIdx.x + s];
      r2[threadIdx.x] += r2[threadIdx.x + s];
    }
    __syncthreads();
  }
  if (threadIdx.x == 0) {
    float mean = r1[0] * (1.f / 65536.f);
    float var = r2[0] * (1.f / 65536.f) - mean * mean;
    stats[idx] = make_float2(mean, rsqrtf(var + EPSV));
  }
}

// ---- MFMA GEMM: out[b,o,n] = sum_c W[o,c]*Xn[b,c,n] + bias[o] (+res) ----
// 128x128 tile, 4 waves x (4x4 of 16x16x32 bf16), BK=32, register prefetch.
template <int XSRC, bool OUTRAW, bool RES>
__global__ __launch_bounds__(256) void mfma_gemm(
    const void* __restrict__ W, const void* __restrict__ Xp,
    const void* __restrict__ xdet, const float2* __restrict__ stats,
    const void* __restrict__ gamma, const void* __restrict__ beta,
    const void* __restrict__ bias, const void* __restrict__ res,
    void* __restrict__ out, int O, int XSB) {
  bool f32 = detect_f32(xdet);
  bool of = OUTRAW && f32;
  int b = blockIdx.z;
  int orow = blockIdx.y << 7;
  int ncol = blockIdx.x << 7;
  int t = threadIdx.x;
  int lane = t & 63, w = t >> 6;
  int wo = (w >> 1) << 6, wn = (w & 1) << 6;
  int l15 = lane & 15, quad = lane >> 4;

  __shared__ __align__(16) u16 Alds[128 * 40];
  __shared__ __align__(16) u16 Blds[128 * 40];

  f32x4 acc[4][4];
#pragma unroll
  for (int i = 0; i < 4; i++)
#pragma unroll
    for (int j = 0; j < 4; j++) acc[i][j] = (f32x4){0.f, 0.f, 0.f, 0.f};

  int ao = t >> 1;            // o-local 0..127
  int ac = (t & 1) << 4;      // c-local 0/16
  int bn0 = (t & 31) << 2;    // n-local
  int bc0 = (t >> 5) << 2;    // c-local
  size_t wrow = (size_t)(orow + ao) * NC;

  uint4 a0, a1;
  uint2 br[4];
  auto preload = [&](int k0) {
    if (f32) {
      const float4* wp = (const float4*)((const float*)W + wrow + k0 + ac);
      float4 v0 = wp[0], v1 = wp[1], v2 = wp[2], v3 = wp[3];
      a0.x = pack2(v0.x, v0.y); a0.y = pack2(v0.z, v0.w);
      a0.z = pack2(v1.x, v1.y); a0.w = pack2(v1.z, v1.w);
      a1.x = pack2(v2.x, v2.y); a1.y = pack2(v2.z, v2.w);
      a1.z = pack2(v3.x, v3.y); a1.w = pack2(v3.z, v3.w);
    } else {
      const uint4* wp = (const uint4*)((const u16*)W + wrow + k0 + ac);
      a0 = wp[0]; a1 = wp[1];
    }
    if (XSRC == 0) {
      float fv[4][4];  // [dc][dn]
#pragma unroll
      for (int dc = 0; dc < 4; dc++) {
        int c = k0 + bc0 + dc;
        size_t xb = ((size_t)b * XSB + c) * NSP + ncol + bn0;
        if (f32) {
          float4 p = *(const float4*)((const float*)Xp + xb);
          fv[dc][0] = p.x; fv[dc][1] = p.y; fv[dc][2] = p.z; fv[dc][3] = p.w;
        } else {
          uint2 p = *(const uint2*)((const u16*)Xp + xb);
          fv[dc][0] = us2f((u16)(p.x & 0xffffu)); fv[dc][1] = us2f((u16)(p.x >> 16));
          fv[dc][2] = us2f((u16)(p.y & 0xffffu)); fv[dc][3] = us2f((u16)(p.y >> 16));
        }
        float2 st = stats[(b << 3) + (c >> 6)];
        float wsc = ld1(gamma, c, f32) * st.y;
        float bsc = ld1(beta, c, f32) - st.x * wsc;
#pragma unroll
        for (int m = 0; m < 4; m++) fv[dc][m] = fmaf(fv[dc][m], wsc, bsc);
      }
#pragma unroll
      for (int dn = 0; dn < 4; dn++) {
        br[dn].x = pack2(fv[0][dn], fv[1][dn]);
        br[dn].y = pack2(fv[2][dn], fv[3][dn]);
      }
    } else {
      u16 bv[4][4];
#pragma unroll
      for (int dc = 0; dc < 4; dc++) {
        int c = k0 + bc0 + dc;
        size_t xb = ((size_t)b * XSB + c) * NSP + ncol + bn0;
        uint2 p = *(const uint2*)((const u16*)Xp + xb);
        bv[dc][0] = (u16)(p.x & 0xffffu); bv[dc][1] = (u16)(p.x >> 16);
        bv[dc][2] = (u16)(p.y & 0xffffu); bv[dc][3] = (u16)(p.y >> 16);
      }
#pragma unroll
      for (int dn = 0; dn < 4; dn++) {
        br[dn].x = bv[0][dn] | ((u32)bv[1][dn] << 16);
        br[dn].y = bv[2][dn] | ((u32)bv[3][dn] << 16);
      }
    }
  };

  preload(0);
  for (int k0 = 0; k0 < NC; k0 += 32) {
    __syncthreads();  // prior chunk's frag reads done
    *(uint4*)&Alds[ao * 40 + ac] = a0;
    *(uint4*)&Alds[ao * 40 + ac + 8] = a1;
#pragma unroll
    for (int dn = 0; dn < 4; dn++) {
      int n = bn0 + dn;
      int addr = n * 40 + (bc0 & 7) + ((((bc0 >> 3) ^ ((n >> 2) & 3))) << 3);
      *(uint2*)&Blds[addr] = br[dn];
    }
    __syncthreads();
    if (k0 + 32 < NC) preload(k0 + 32);  // overlap next loads with MFMA
    short8 af[4], bf[4];
#pragma unroll
    for (int ot = 0; ot < 4; ot++)
      af[ot] = *(const short8*)&Alds[(wo + ot * 16 + l15) * 40 + (quad << 3)];
#pragma unroll
    for (int nt = 0; nt < 4; nt++) {
      int n = wn + nt * 16 + l15;
      int blk = quad ^ ((n >> 2) & 3);
      bf[nt] = *(const short8*)&Blds[n * 40 + (blk << 3)];
    }
#pragma unroll
    for (int ot = 0; ot < 4; ot++)
#pragma unroll
      for (int nt = 0; nt < 4; nt++)
        acc[ot][nt] = __builtin_amdgcn_mfma_f32_16x16x32_bf16(
            af[ot], bf[nt], acc[ot][nt], 0, 0, 0);
  }
  // ---- epilogue ----
#pragma unroll
  for (int ot = 0; ot < 4; ot++) {
#pragma unroll
    for (int r = 0; r < 4; r++) {
      int o = orow + wo + ot * 16 + (quad << 2) + r;
      float bs = ld1(bias, o, f32);
      size_t rowb = ((size_t)b * O + o) * NSP + ncol + wn + l15;
#pragma unroll
      for (int nt = 0; nt < 4; nt++) {
        size_t idx = rowb + nt * 16;
        float v = acc[ot][nt][r] + bs;
        if (RES) v += ld1(res, idx, f32);
        if (of) ((float*)out)[idx] = v;
        else ((u16*)out)[idx] = f2us(v);
      }
    }
  }
}

// ---- MFMA attention: block = 128 q of one (b,h); wave = 32 q; m-chunk 64.
// S^T = K.Q so P lands m-contiguous per lane: b64 P-writes, b128 PV reads.
__global__ __launch_bounds__(256) void attn_kernel(u16* qkv) {
  int blk = blockIdx.x;
  int b = blk >> 6;
  int h = (blk >> 3) & 7;
  int q0 = (blk & 7) << 7;
  int t = threadIdx.x;
  int lane = t & 63, w = t >> 6;
  int l15 = lane & 15, quad = lane >> 4;

  __shared__ __align__(16) u16 Klds[64 * 72];     // [m][d]
  __shared__ __align__(16) u16 Vlds[64 * 72];     // [d][m]
  __shared__ __align__(16) u16 Plds[4][32 * 72];  // per-wave [q][m]

  size_t hb = (size_t)b * OQKV + h * 64;

  // Q frags (B-operand: lane=q, k=d), pre-scaled by 1/64 (exact in bf16)
  short8 qf[2][2];
#pragma unroll
  for (int qt = 0; qt < 2; qt++)
#pragma unroll
    for (int ds = 0; ds < 2; ds++) {
      int q = q0 + (w << 5) + (qt << 4) + l15;
#pragma unroll
      for (int j = 0; j < 8; j++) {
        int d = (ds << 5) + (quad << 3) + j;
        qf[qt][ds][j] = (short)f2us(us2f(qkv[(hb + d) * NSP + q]) * 0.015625f);
      }
    }

  f32x4 oacc[2][4];
#pragma unroll
  for (int qt = 0; qt < 2; qt++)
#pragma unroll
    for (int dd = 0; dd < 4; dd++) oacc[qt][dd] = (f32x4){0.f, 0.f, 0.f, 0.f};
  float lsum[2] = {0.f, 0.f};

  int m0k = (t & 15) << 2;   // K-staging m
  int d0k = (t >> 4) << 2;   // K-staging d
  int sdv = t >> 2;          // V-staging d
  int sm0 = (t & 3) << 4;    // V-staging m
  const u16* kbase = qkv + (hb + 512) * NSP;
  const u16* vbase = qkv + (hb + 1024 + sdv) * NSP;
  u16* pmy = Plds[w];

  uint2 kr[4];
  uint4 vr0, vr1;
  auto preload = [&](int mc) {
#pragma unroll
    for (int i = 0; i < 4; i++)
      kr[i] = *(const uint2*)(kbase + (size_t)(d0k + i) * NSP + mc + m0k);
    vr0 = *(const uint4*)(vbase + mc + sm0);
    vr1 = *(const uint4*)(vbase + mc + sm0 + 8);
  };

  preload(0);
  for (int mc = 0; mc < NSP; mc += 64) {
    __syncthreads();  // prior chunk's K/V frag reads done
    // K: 4x4 register transpose -> [m][d] b64 writes
#pragma unroll
    for (int j = 0; j < 4; j++) {
      u32 s0 = (j & 2) ? kr[0].y : kr[0].x;
      u32 s1 = (j & 2) ? kr[1].y : kr[1].x;
      u32 s2 = (j & 2) ? kr[2].y : kr[2].x;
      u32 s3 = (j & 2) ? kr[3].y : kr[3].x;
      int sh = (j & 1) << 4;
      uint2 wv;
      wv.x = ((s0 >> sh) & 0xffffu) | (((s1 >> sh) & 0xffffu) << 16);
      wv.y = ((s2 >> sh) & 0xffffu) | (((s3 >> sh) & 0xffffu) << 16);
      *(uint2*)&Klds[(m0k + j) * 72 + d0k] = wv;
    }
    *(uint4*)&Vlds[sdv * 72 + sm0] = vr0;
    *(uint4*)&Vlds[sdv * 72 + sm0 + 8] = vr1;
    __syncthreads();
    if (mc + 64 < NSP) preload(mc + 64);  // overlap next loads with MFMA
    // ---- S^T = K.Q : D[m][q], then exp + b64 P-write ----
#pragma unroll
    for (int kg = 0; kg < 4; kg++) {
      short8 kf0 = *(const short8*)&Klds[((kg << 4) + l15) * 72 + (quad << 3)];
      short8 kf1 = *(const short8*)&Klds[((kg << 4) + l15) * 72 + 32 + (quad << 3)];
#pragma unroll
      for (int qt = 0; qt < 2; qt++) {
        f32x4 z = (f32x4){0.f, 0.f, 0.f, 0.f};
        z = __builtin_amdgcn_mfma_f32_16x16x32_bf16(kf0, qf[qt][0], z, 0, 0, 0);
        z = __builtin_amdgcn_mfma_f32_16x16x32_bf16(kf1, qf[qt][1], z, 0, 0, 0);
        float p0 = __expf(z[0]), p1 = __expf(z[1]);
        float p2 = __expf(z[2]), p3 = __expf(z[3]);
        lsum[qt] += (p0 + p1) + (p2 + p3);
        uint2 pw;
        pw.x = pack2(p0, p1); pw.y = pack2(p2, p3);
        *(uint2*)&pmy[((qt << 4) + l15) * 72 + (kg << 4) + (quad << 2)] = pw;
      }
    }
    // ---- PV: O[d][q] += V[d][m] P^T[m][q] ----
#pragma unroll
    for (int mg = 0; mg < 2; mg++) {
      short8 pf0 = *(const short8*)&pmy[l15 * 72 + (mg << 5) + (quad << 3)];
      short8 pf1 = *(const short8*)&pmy[(16 + l15) * 72 + (mg << 5) + (quad << 3)];
#pragma unroll
      for (int dd = 0; dd < 4; dd++) {
        short8 vf = *(const short8*)&Vlds[((dd << 4) + l15) * 72 + (mg << 5) + (quad << 3)];
        oacc[0][dd] = __builtin_amdgcn_mfma_f32_16x16x32_bf16(vf, pf0, oacc[0][dd], 0, 0, 0);
        oacc[1][dd] = __builtin_amdgcn_mfma_f32_16x16x32_bf16(vf, pf1, oacc[1][dd], 0, 0, 0);
      }
    }
  }
  // ---- normalize + in-place store ----
  float invL[2];
#pragma unroll
  for (int qt = 0; qt < 2; qt++) {
    float v = lsum[qt];
    v += __shfl_xor(v, 16);
    v += __shfl_xor(v, 32);
    invL[qt] = 1.0f / v;
  }
#pragma unroll
  for (int qt = 0; qt < 2; qt++) {
    int q = q0 + (w << 5) + (qt << 4) + l15;
#pragma unroll
    for (int dd = 0; dd < 4; dd++)
#pragma unroll
      for (int r = 0; r < 4; r++) {
        int d = (dd << 4) + (quad << 2) + r;
        qkv[(hb + d) * NSP + q] = f2us(oacc[qt][dd][r] * invL[qt]);
      }
  }
}

extern "C" void kernel_launch(void* const* d_in, const int* in_sizes, int n_in,
                              void* d_out, int out_size, void* d_ws, size_t ws_size,
                              hipStream_t stream) {
  const void* x      = d_in[0];
  const void* norm_w = d_in[1];
  const void* norm_b = d_in[2];
  const void* qkv_w  = d_in[3];
  const void* qkv_b  = d_in[4];
  const void* proj_w = d_in[5];
  const void* proj_b = d_in[6];

  char* ws = (char*)d_ws;
  float2* stats = (float2*)ws;           // [B*8] (mean, inv)
  u16* qkv = (u16*)(ws + 4096);          // 48 MB: [B, 3C, N] bf16

  gn_stats_kernel<<<NB * 8, 256, 0, stream>>>(x, stats);
  mfma_gemm<0, false, false><<<dim3(8, 12, NB), 256, 0, stream>>>(
      qkv_w, x, x, stats, norm_w, norm_b, qkv_b, nullptr, qkv, OQKV, NC);
  attn_kernel<<<1024, 256, 0, stream>>>(qkv);
  mfma_gemm<1, true, true><<<dim3(8, 4, NB), 256, 0, stream>>>(
      proj_w, qkv, x, nullptr, nullptr, nullptr, proj_b, x, d_out, NC, OQKV);
}

// Round 7
// 289.923 us; speedup vs baseline: 1.0801x; 1.0801x over previous
//
#include <hip/hip_runtime.h>

#define NB 16
#define NC 512
#define NSP 1024
#define OQKV 1536
#define EPSV 1e-5f

typedef unsigned short u16;
typedef unsigned int u32;
typedef __attribute__((ext_vector_type(8))) short short8;
typedef __attribute__((ext_vector_type(4))) float f32x4;

__device__ __forceinline__ float us2f(u16 u) {
  return __uint_as_float(((u32)u) << 16);
}
__device__ __forceinline__ u16 f2us(float f) {  // RNE f32->bf16
  u32 x = __float_as_uint(f);
  return (u16)((x + 0x7fffu + ((x >> 16) & 1u)) >> 16);
}
#if __has_builtin(__builtin_amdgcn_cvt_pk_bf16_f32)
typedef __attribute__((ext_vector_type(2))) __bf16 bf16x2_t;
__device__ __forceinline__ u32 pack2(float a, float b) {
  bf16x2_t r = __builtin_amdgcn_cvt_pk_bf16_f32(a, b);
  return *reinterpret_cast<u32*>(&r);
}
#else
__device__ __forceinline__ u32 pack2(float a, float b) {
  return (u32)f2us(a) | ((u32)f2us(b) << 16);
}
#endif
__device__ __forceinline__ float ld1(const void* p, size_t i, bool f32) {
  return f32 ? ((const float*)p)[i] : us2f(((const u16*)p)[i]);
}
// wave-uniform input-dtype detection (fp32 low-halves are random mantissa)
__device__ __forceinline__ bool detect_f32(const void* x0) {
  const u32* xw = (const u32*)x0;
  u32 w = xw[threadIdx.x & 63];
  u32 e = ((w & 0xffffu) >> 7) & 0xffu;
  bool sane = (e >= 0x60u && e <= 0x9fu);
  return __popcll(__ballot(sane)) < 32;
}

// ---- GroupNorm partial sums: one block per (b,g,half); 32768 elems ----
__global__ __launch_bounds__(256) void gn_partial(
    const void* __restrict__ x, float2* __restrict__ part) {
  bool f32 = detect_f32(x);
  int idx = blockIdx.x;
  size_t base = (size_t)idx * 32768;
  float s1 = 0.f, s2 = 0.f;
  for (int i = threadIdx.x; i < 4096; i += 256) {
    float f[8];
    if (f32) {
      float4 a = *((const float4*)x + (base >> 2) + i * 2);
      float4 b = *((const float4*)x + (base >> 2) + i * 2 + 1);
      f[0]=a.x; f[1]=a.y; f[2]=a.z; f[3]=a.w; f[4]=b.x; f[5]=b.y; f[6]=b.z; f[7]=b.w;
    } else {
      uint4 p = *((const uint4*)x + (base >> 3) + i);
      f[0]=us2f((u16)(p.x&0xffffu)); f[1]=us2f((u16)(p.x>>16));
      f[2]=us2f((u16)(p.y&0xffffu)); f[3]=us2f((u16)(p.y>>16));
      f[4]=us2f((u16)(p.z&0xffffu)); f[5]=us2f((u16)(p.z>>16));
      f[6]=us2f((u16)(p.w&0xffffu)); f[7]=us2f((u16)(p.w>>16));
    }
#pragma unroll
    for (int m = 0; m < 8; m++) { s1 += f[m]; s2 += f[m] * f[m]; }
  }
  __shared__ float r1[256], r2[256];
  r1[threadIdx.x] = s1; r2[threadIdx.x] = s2;
  __syncthreads();
  for (int s = 128; s > 0; s >>= 1) {
    if ((int)threadIdx.x < s) {
      r1[threadIdx.x] += r1[threadIdx.x + s];
      r2[threadIdx.x] += r2[threadIdx.x + s];
    }
    __syncthreads();
  }
  if (threadIdx.x == 0) part[idx] = make_float2(r1[0], r2[0]);
}
__global__ void gn_combine(const float2* __restrict__ part,
                           float2* __restrict__ stats) {
  int i = threadIdx.x;  // 0..127
  float2 a = part[2 * i], b = part[2 * i + 1];
  float mean = (a.x + b.x) * (1.f / 65536.f);
  float var = (a.y + b.y) * (1.f / 65536.f) - mean * mean;
  stats[i] = make_float2(mean, rsqrtf(var + EPSV));
}

// ---- MFMA GEMM: out[b,o,n] = sum_c W[o,c]*Xn[b,c,n] + bias[o] (+res) ----
// 128x128 tile, 4 waves x (4x4 of 16x16x32 bf16), BK=32, stride 72, no
// swizzle: B staged as [n][c] rows via 8c x 2n dword gathers + b128 writes
// (conflict-free writes AND reads; r6's XOR swizzle caused read conflicts).
template <int XSRC, bool OUTRAW, bool RES>
__global__ __launch_bounds__(256) void mfma_gemm(
    const void* __restrict__ W, const void* __restrict__ Xp,
    const void* __restrict__ xdet, const float2* __restrict__ stats,
    const void* __restrict__ gamma, const void* __restrict__ beta,
    const void* __restrict__ bias, const void* __restrict__ res,
    void* __restrict__ out, int O, int XSB) {
  bool f32 = detect_f32(xdet);
  bool of = OUTRAW && f32;
  int b = blockIdx.z;
  int orow = blockIdx.y << 7;
  int ncol = blockIdx.x << 7;
  int t = threadIdx.x;
  int lane = t & 63, w = t >> 6;
  int wo = (w >> 1) << 6, wn = (w & 1) << 6;
  int l15 = lane & 15, quad = lane >> 4;

  __shared__ __align__(16) u16 Alds[128 * 72];
  __shared__ __align__(16) u16 Blds[128 * 72];

  f32x4 acc[4][4];
#pragma unroll
  for (int i = 0; i < 4; i++)
#pragma unroll
    for (int j = 0; j < 4; j++) acc[i][j] = (f32x4){0.f, 0.f, 0.f, 0.f};

  int ao = t >> 1;            // o-local 0..127
  int ac = (t & 1) << 4;      // c-local 0/16
  int bn = (t & 63) << 1;     // n-local, 2 rows per thread
  int cb = (t >> 6) << 3;     // c-local 8-block
  size_t wrow = (size_t)(orow + ao) * NC;

  for (int k0 = 0; k0 < NC; k0 += 32) {
    // ---- A tile loads ----
    uint4 a0, a1;
    if (f32) {
      const float4* wp = (const float4*)((const float*)W + wrow + k0 + ac);
      float4 v0 = wp[0], v1 = wp[1], v2 = wp[2], v3 = wp[3];
      a0.x = pack2(v0.x, v0.y); a0.y = pack2(v0.z, v0.w);
      a0.z = pack2(v1.x, v1.y); a0.w = pack2(v1.z, v1.w);
      a1.x = pack2(v2.x, v2.y); a1.y = pack2(v2.z, v2.w);
      a1.z = pack2(v3.x, v3.y); a1.w = pack2(v3.z, v3.w);
    } else {
      const uint4* wp = (const uint4*)((const u16*)W + wrow + k0 + ac);
      a0 = wp[0]; a1 = wp[1];
    }
    // ---- B tile loads: 8 c x 2 n per thread ----
    uint4 r0, r1;
    {
      int c0 = k0 + cb;
      size_t xb = ((size_t)b * XSB + c0) * NSP + ncol + bn;
      if (XSRC == 0) {
        float f0[8], f1[8];
        if (f32) {
#pragma unroll
          for (int j = 0; j < 8; j++) {
            float2 p = *(const float2*)((const float*)Xp + xb + (size_t)j * NSP);
            f0[j] = p.x; f1[j] = p.y;
          }
        } else {
#pragma unroll
          for (int j = 0; j < 8; j++) {
            u32 p = *(const u32*)((const u16*)Xp + xb + (size_t)j * NSP);
            f0[j] = us2f((u16)(p & 0xffffu)); f1[j] = us2f((u16)(p >> 16));
          }
        }
        float2 st = stats[(b << 3) + (c0 >> 6)];
        float g[8], be[8];
        if (f32) {
          float4 ga = *(const float4*)((const float*)gamma + c0);
          float4 gb = *(const float4*)((const float*)gamma + c0 + 4);
          float4 ba = *(const float4*)((const float*)beta + c0);
          float4 bb = *(const float4*)((const float*)beta + c0 + 4);
          g[0]=ga.x; g[1]=ga.y; g[2]=ga.z; g[3]=ga.w;
          g[4]=gb.x; g[5]=gb.y; g[6]=gb.z; g[7]=gb.w;
          be[0]=ba.x; be[1]=ba.y; be[2]=ba.z; be[3]=ba.w;
          be[4]=bb.x; be[5]=bb.y; be[6]=bb.z; be[7]=bb.w;
        } else {
          uint4 gv = *(const uint4*)((const u16*)gamma + c0);
          uint4 bv = *(const uint4*)((const u16*)beta + c0);
          g[0]=us2f((u16)(gv.x&0xffffu)); g[1]=us2f((u16)(gv.x>>16));
          g[2]=us2f((u16)(gv.y&0xffffu)); g[3]=us2f((u16)(gv.y>>16));
          g[4]=us2f((u16)(gv.z&0xffffu)); g[5]=us2f((u16)(gv.z>>16));
          g[6]=us2f((u16)(gv.w&0xffffu)); g[7]=us2f((u16)(gv.w>>16));
          be[0]=us2f((u16)(bv.x&0xffffu)); be[1]=us2f((u16)(bv.x>>16));
          be[2]=us2f((u16)(bv.y&0xffffu)); be[3]=us2f((u16)(bv.y>>16));
          be[4]=us2f((u16)(bv.z&0xffffu)); be[5]=us2f((u16)(bv.z>>16));
          be[6]=us2f((u16)(bv.w&0xffffu)); be[7]=us2f((u16)(bv.w>>16));
        }
#pragma unroll
        for (int j = 0; j < 8; j++) {
          float wsc = g[j] * st.y;
          float bsc = be[j] - st.x * wsc;
          f0[j] = fmaf(f0[j], wsc, bsc);
          f1[j] = fmaf(f1[j], wsc, bsc);
        }
        r0.x = pack2(f0[0], f0[1]); r0.y = pack2(f0[2], f0[3]);
        r0.z = pack2(f0[4], f0[5]); r0.w = pack2(f0[6], f0[7]);
        r1.x = pack2(f1[0], f1[1]); r1.y = pack2(f1[2], f1[3]);
        r1.z = pack2(f1[4], f1[5]); r1.w = pack2(f1[6], f1[7]);
      } else {
        u32 p[8];
#pragma unroll
        for (int j = 0; j < 8; j++)
          p[j] = *(const u32*)((const u16*)Xp + xb + (size_t)j * NSP);
        r0.x = (p[0] & 0xffffu) | (p[1] << 16);
        r0.y = (p[2] & 0xffffu) | (p[3] << 16);
        r0.z = (p[4] & 0xffffu) | (p[5] << 16);
        r0.w = (p[6] & 0xffffu) | (p[7] << 16);
        r1.x = (p[0] >> 16) | (p[1] & 0xffff0000u);
        r1.y = (p[2] >> 16) | (p[3] & 0xffff0000u);
        r1.z = (p[4] >> 16) | (p[5] & 0xffff0000u);
        r1.w = (p[6] >> 16) | (p[7] & 0xffff0000u);
      }
    }
    __syncthreads();  // prior chunk's frag reads done
    *(uint4*)&Alds[ao * 72 + ac] = a0;
    *(uint4*)&Alds[ao * 72 + ac + 8] = a1;
    *(uint4*)&Blds[bn * 72 + cb] = r0;
    *(uint4*)&Blds[(bn + 1) * 72 + cb] = r1;
    __syncthreads();
    short8 af[4], bf[4];
#pragma unroll
    for (int ot = 0; ot < 4; ot++)
      af[ot] = *(const short8*)&Alds[(wo + ot * 16 + l15) * 72 + (quad << 3)];
#pragma unroll
    for (int nt = 0; nt < 4; nt++)
      bf[nt] = *(const short8*)&Blds[(wn + nt * 16 + l15) * 72 + (quad << 3)];
#pragma unroll
    for (int ot = 0; ot < 4; ot++)
#pragma unroll
      for (int nt = 0; nt < 4; nt++)
        acc[ot][nt] = __builtin_amdgcn_mfma_f32_16x16x32_bf16(
            af[ot], bf[nt], acc[ot][nt], 0, 0, 0);
  }
  // ---- epilogue ----
#pragma unroll
  for (int ot = 0; ot < 4; ot++) {
#pragma unroll
    for (int r = 0; r < 4; r++) {
      int o = orow + wo + ot * 16 + (quad << 2) + r;
      float bs = ld1(bias, o, f32);
      size_t rowb = ((size_t)b * O + o) * NSP + ncol + wn + l15;
#pragma unroll
      for (int nt = 0; nt < 4; nt++) {
        size_t idx = rowb + nt * 16;
        float v = acc[ot][nt][r] + bs;
        if (RES) v += ld1(res, idx, f32);
        if (of) ((float*)out)[idx] = v;
        else ((u16*)out)[idx] = f2us(v);
      }
    }
  }
}

// ---- MFMA attention: 512-thread block = 256 q of one (b,h); 8 waves. ----
// Waves 0-3 stage K (register transpose), waves 4-7 stage V. S^T = K.Q,
// P per-wave LDS round-trip, PV. Output in-place into q-slice.
__global__ __launch_bounds__(512, 4) void attn_kernel(u16* qkv) {
  int blk = blockIdx.x;
  int b = blk >> 5;
  int h = (blk >> 2) & 7;
  int q0 = (blk & 3) << 8;
  int t = threadIdx.x;
  int lane = t & 63, w = t >> 6;
  int l15 = lane & 15, quad = lane >> 4;

  __shared__ __align__(16) u16 Klds[64 * 72];     // [m][d]
  __shared__ __align__(16) u16 Vlds[64 * 72];     // [d][m]
  __shared__ __align__(16) u16 Plds[8][32 * 72];  // per-wave [q][m]

  size_t hb = (size_t)b * OQKV + h * 64;

  // Q frags (B-operand: lane=q, k=d), pre-scaled by 1/64 (exact in bf16)
  short8 qf[2][2];
#pragma unroll
  for (int qt = 0; qt < 2; qt++)
#pragma unroll
    for (int ds = 0; ds < 2; ds++) {
      int q = q0 + (w << 5) + (qt << 4) + l15;
#pragma unroll
      for (int j = 0; j < 8; j++) {
        int d = (ds << 5) + (quad << 3) + j;
        qf[qt][ds][j] = (short)f2us(us2f(qkv[(hb + d) * NSP + q]) * 0.015625f);
      }
    }

  f32x4 oacc[2][4];
#pragma unroll
  for (int qt = 0; qt < 2; qt++)
#pragma unroll
    for (int dd = 0; dd < 4; dd++) oacc[qt][dd] = (f32x4){0.f, 0.f, 0.f, 0.f};
  float lsum[2] = {0.f, 0.f};

  bool isK = (t < 256);        // wave-uniform staging split
  int ts = t & 255;
  int m0k = (ts & 15) << 2;    // K-staging m
  int d0k = (ts >> 4) << 2;    // K-staging d
  int sdv = ts >> 2;           // V-staging d
  int sm0 = (ts & 3) << 4;     // V-staging m
  const u16* kbase = qkv + (hb + 512) * NSP;
  const u16* vbase = qkv + (hb + 1024 + sdv) * NSP;
  u16* pmy = Plds[w];

  uint2 kr[4];
  uint4 vr0, vr1;
  auto preload = [&](int mc) {
    if (isK) {
#pragma unroll
      for (int i = 0; i < 4; i++)
        kr[i] = *(const uint2*)(kbase + (size_t)(d0k + i) * NSP + mc + m0k);
    } else {
      vr0 = *(const uint4*)(vbase + mc + sm0);
      vr1 = *(const uint4*)(vbase + mc + sm0 + 8);
    }
  };

  preload(0);
  for (int mc = 0; mc < NSP; mc += 64) {
    __syncthreads();  // prior chunk's K/V frag reads done
    if (isK) {
      // K: 4x4 register transpose -> [m][d] b64 writes
#pragma unroll
      for (int j = 0; j < 4; j++) {
        u32 s0 = (j & 2) ? kr[0].y : kr[0].x;
        u32 s1 = (j & 2) ? kr[1].y : kr[1].x;
        u32 s2 = (j & 2) ? kr[2].y : kr[2].x;
        u32 s3 = (j & 2) ? kr[3].y : kr[3].x;
        int sh = (j & 1) << 4;
        uint2 wv;
        wv.x = ((s0 >> sh) & 0xffffu) | (((s1 >> sh) & 0xffffu) << 16);
        wv.y = ((s2 >> sh) & 0xffffu) | (((s3 >> sh) & 0xffffu) << 16);
        *(uint2*)&Klds[(m0k + j) * 72 + d0k] = wv;
      }
    } else {
      *(uint4*)&Vlds[sdv * 72 + sm0] = vr0;
      *(uint4*)&Vlds[sdv * 72 + sm0 + 8] = vr1;
    }
    __syncthreads();
    if (mc + 64 < NSP) preload(mc + 64);  // overlap next loads with MFMA
    // ---- S^T = K.Q : D[m][q], then exp + b64 P-write ----
#pragma unroll
    for (int kg = 0; kg < 4; kg++) {
      short8 kf0 = *(const short8*)&Klds[((kg << 4) + l15) * 72 + (quad << 3)];
      short8 kf1 = *(const short8*)&Klds[((kg << 4) + l15) * 72 + 32 + (quad << 3)];
#pragma unroll
      for (int qt = 0; qt < 2; qt++) {
        f32x4 z = (f32x4){0.f, 0.f, 0.f, 0.f};
        z = __builtin_amdgcn_mfma_f32_16x16x32_bf16(kf0, qf[qt][0], z, 0, 0, 0);
        z = __builtin_amdgcn_mfma_f32_16x16x32_bf16(kf1, qf[qt][1], z, 0, 0, 0);
        float p0 = __expf(z[0]), p1 = __expf(z[1]);
        float p2 = __expf(z[2]), p3 = __expf(z[3]);
        lsum[qt] += (p0 + p1) + (p2 + p3);
        uint2 pw;
        pw.x = pack2(p0, p1); pw.y = pack2(p2, p3);
        *(uint2*)&pmy[((qt << 4) + l15) * 72 + (kg << 4) + (quad << 2)] = pw;
      }
    }
    // ---- PV: O[d][q] += V[d][m] P^T[m][q] ----
#pragma unroll
    for (int mg = 0; mg < 2; mg++) {
      short8 pf0 = *(const short8*)&pmy[l15 * 72 + (mg << 5) + (quad << 3)];
      short8 pf1 = *(const short8*)&pmy[(16 + l15) * 72 + (mg << 5) + (quad << 3)];
#pragma unroll
      for (int dd = 0; dd < 4; dd++) {
        short8 vf = *(const short8*)&Vlds[((dd << 4) + l15) * 72 + (mg << 5) + (quad << 3)];
        oacc[0][dd] = __builtin_amdgcn_mfma_f32_16x16x32_bf16(vf, pf0, oacc[0][dd], 0, 0, 0);
        oacc[1][dd] = __builtin_amdgcn_mfma_f32_16x16x32_bf16(vf, pf1, oacc[1][dd], 0, 0, 0);
      }
    }
  }
  // ---- normalize + in-place store ----
  float invL[2];
#pragma unroll
  for (int qt = 0; qt < 2; qt++) {
    float v = lsum[qt];
    v += __shfl_xor(v, 16);
    v += __shfl_xor(v, 32);
    invL[qt] = 1.0f / v;
  }
#pragma unroll
  for (int qt = 0; qt < 2; qt++) {
    int q = q0 + (w << 5) + (qt << 4) + l15;
#pragma unroll
    for (int dd = 0; dd < 4; dd++)
#pragma unroll
      for (int r = 0; r < 4; r++) {
        int d = (dd << 4) + (quad << 2) + r;
        qkv[(hb + d) * NSP + q] = f2us(oacc[qt][dd][r] * invL[qt]);
      }
  }
}

extern "C" void kernel_launch(void* const* d_in, const int* in_sizes, int n_in,
                              void* d_out, int out_size, void* d_ws, size_t ws_size,
                              hipStream_t stream) {
  const void* x      = d_in[0];
  const void* norm_w = d_in[1];
  const void* norm_b = d_in[2];
  const void* qkv_w  = d_in[3];
  const void* qkv_b  = d_in[4];
  const void* proj_w = d_in[5];
  const void* proj_b = d_in[6];

  char* ws = (char*)d_ws;
  float2* part  = (float2*)ws;             // [256] partial (s1,s2)
  float2* stats = (float2*)(ws + 2048);    // [128] (mean, inv)
  u16* qkv = (u16*)(ws + 4096);            // 48 MB: [B, 3C, N] bf16

  gn_partial<<<256, 256, 0, stream>>>(x, part);
  gn_combine<<<1, 128, 0, stream>>>(part, stats);
  mfma_gemm<0, false, false><<<dim3(8, 12, NB), 256, 0, stream>>>(
      qkv_w, x, x, stats, norm_w, norm_b, qkv_b, nullptr, qkv, OQKV, NC);
  attn_kernel<<<512, 512, 0, stream>>>(qkv);
  mfma_gemm<1, true, true><<<dim3(8, 4, NB), 256, 0, stream>>>(
      proj_w, qkv, x, nullptr, nullptr, nullptr, proj_b, x, d_out, NC, OQKV);
}